// Round 9
// baseline (34.045 us; speedup 1.0000x reference)
//
#include <hip/hip_runtime.h>

#define PAD 2
#define PXT 2                 // pixels per thread along x
#define BDX 16
#define BDY 16
#define TSX (BDX * PXT)       // 32 outputs wide per block
#define TSY BDY               // 16 outputs high per block
#define LTW (TSX + 2 * PAD)   // 36 floats per LDS row (9 float4 chunks)
#define LTH (TSY + 2 * PAD)   // 20 rows
#define NCHUNK (LTH * LTW / 4) // 180

typedef float float4u __attribute__((vector_size(16), aligned(4)));
typedef float v2f __attribute__((ext_vector_type(2)));

__device__ __forceinline__ float min3f(float a, float b, float c) {
    return fminf(fminf(a, b), c);   // fuses to v_min3_f32
}
__device__ __forceinline__ float max3f(float a, float b, float c) {
    return fmaxf(fmaxf(a, b), c);   // fuses to v_max3_f32
}
__device__ __forceinline__ float med3f(float a, float b, float c) {
    return fmaxf(fminf(a, b), fminf(fmaxf(a, b), c));  // v_med3_f32 pattern
}

#define CE(a, b) { float _lo = fminf(a, b), _hi = fmaxf(a, b); (a) = _lo; (b) = _hi; }

// median of 9 in q4 (Devillard 19-CE network)
#define MED9(q0, q1, q2, q3, q4, q5, q6, q7, q8) \
    CE(q1, q2) CE(q4, q5) CE(q7, q8) \
    CE(q0, q1) CE(q3, q4) CE(q6, q7) \
    CE(q1, q2) CE(q4, q5) CE(q7, q8) \
    CE(q0, q3) CE(q5, q8) CE(q4, q7) \
    CE(q3, q6) CE(q1, q4) CE(q2, q5) \
    CE(q4, q7) CE(q4, q2) CE(q6, q4) \
    CE(q4, q2)

__global__ __launch_bounds__(256) void denoise_median5_kernel(
    const float* __restrict__ x,
    const float* __restrict__ noise_var_p,
    const float* __restrict__ noise_bias_p,
    float* __restrict__ out,
    int H, int W)
{
    __shared__ float tile[LTH][LTW];   // 2880 B

    const float noise_var  = noise_var_p[0];
    const float noise_bias = noise_bias_p[0];

    const int b      = blockIdx.z;
    const int tile_y = blockIdx.y * TSY;
    const int tile_x = blockIdx.x * TSX;
    const int tx = threadIdx.x;
    const int ty = threadIdx.y;
    const int tid = ty * BDX + tx;

    const float* __restrict__ img = x + (size_t)b * H * W;

    const bool interior = (blockIdx.x > 0) && (blockIdx.x < gridDim.x - 1) &&
                          (blockIdx.y > 0) && (blockIdx.y < gridDim.y - 1);
    if (interior) {
        // 180 float4 chunks; one per thread for tid<180. 4B-aligned global ok.
        if (tid < NCHUNK) {
            const int row = tid / 9;
            const int cc  = tid - row * 9;
            const float* gsrc = img + (size_t)(tile_y - PAD + row) * W + (tile_x - PAD) + cc * 4;
            *(float4u*)&tile[row][cc * 4] = *(const float4u*)gsrc;
        }
    } else {
        // Edge blocks: scalar bounds-checked staging (zero pad outside image).
        for (int i = tid; i < LTH * LTW; i += BDX * BDY) {
            const int ly = i / LTW;
            const int lx = i - ly * LTW;
            const int gy = tile_y + ly - PAD;
            const int gx = tile_x + lx - PAD;
            float v = 0.0f;
            if ((unsigned)gy < (unsigned)H && (unsigned)gx < (unsigned)W)
                v = img[(size_t)gy * W + gx];
            tile[ly][lx] = v;
        }
    }
    __syncthreads();

    // 6 columns x 5 rows per thread, via 3x ds_read_b64 per row (8B aligned).
    float c[6][5];
    #pragma unroll
    for (int r = 0; r < 5; ++r) {
        const v2f a = *(const v2f*)&tile[ty + r][tx * PXT + 0];
        const v2f d = *(const v2f*)&tile[ty + r][tx * PXT + 2];
        const v2f e = *(const v2f*)&tile[ty + r][tx * PXT + 4];
        c[0][r] = a.x; c[1][r] = a.y;
        c[2][r] = d.x; c[3][r] = d.y;
        c[4][r] = e.x; c[5][r] = e.y;
    }

    // Center pixels (raw, before in-place column sorts).
    const float center0 = c[2][2];
    const float center1 = c[3][2];

    // Sort all 6 columns in place (15-op min3/max3/med3 network).
    #pragma unroll
    for (int k = 0; k < 6; ++k) {
        const float a1 = fminf(c[k][0], c[k][1]), a2 = fmaxf(c[k][0], c[k][1]);
        const float b1 = fminf(c[k][2], c[k][3]), b2 = fmaxf(c[k][2], c[k][3]);
        const float cc = c[k][4];
        const float t1 = fminf(a2, b2), t3 = fmaxf(a1, b1);
        const float M  = fmaxf(a2, b2), m  = fminf(a1, b1);
        c[k][0] = fminf(m, cc);
        c[k][4] = fmaxf(M, cc);
        c[k][2] = med3f(t1, t3, cc);
        c[k][3] = max3f(t1, fminf(cc, M), t3);
        c[k][1] = min3f(t3, fmaxf(cc, m), t1);
    }

    // Column sums / sums-of-squares from the SORTED columns (sum invariant).
    float sc[6], qc[6];
    #pragma unroll
    for (int k = 0; k < 6; ++k) {
        sc[k] = ((c[k][0] + c[k][1]) + (c[k][2] + c[k][3])) + c[k][4];
        float qq = c[k][0] * c[k][0];
        qq = fmaf(c[k][1], c[k][1], qq);
        qq = fmaf(c[k][2], c[k][2], qq);
        qq = fmaf(c[k][3], c[k][3], qq);
        qc[k] = fmaf(c[k][4], c[k][4], qq);
    }
    const float sum0 = ((sc[0] + sc[1]) + (sc[2] + sc[3])) + sc[4];
    const float sq0  = ((qc[0] + qc[1]) + (qc[2] + qc[3])) + qc[4];
    const float sum1 = sum0 - sc[0] + sc[5];
    const float sq1  = sq0  - qc[0] + qc[5];

    v2f res;

    #pragma unroll
    for (int p = 0; p < PXT; ++p) {
        float A1, A2, B1, B2, B3, C1, C2, C3, D1, D2, D3, E1, E2;
        // row 0 (column minima): sorted pos 3,4
        {
            const float a1 = fminf(c[p][0], c[p+1][0]), a2 = fmaxf(c[p][0], c[p+1][0]);
            const float b1 = fminf(c[p+2][0], c[p+3][0]), b2 = fmaxf(c[p+2][0], c[p+3][0]);
            const float cc = c[p+4][0];
            const float M = fmaxf(a2, b2), t1 = fminf(a2, b2), t3 = fmaxf(a1, b1);
            A2 = fmaxf(M, cc);
            A1 = max3f(t1, fminf(cc, M), t3);
        }
        // row 1: sorted pos 2,3,4
        {
            const float a1 = fminf(c[p][1], c[p+1][1]), a2 = fmaxf(c[p][1], c[p+1][1]);
            const float b1 = fminf(c[p+2][1], c[p+3][1]), b2 = fmaxf(c[p+2][1], c[p+3][1]);
            const float cc = c[p+4][1];
            const float M = fmaxf(a2, b2), t1 = fminf(a2, b2), t3 = fmaxf(a1, b1);
            B3 = fmaxf(M, cc);
            B2 = max3f(t1, fminf(cc, M), t3);
            B1 = med3f(t1, t3, cc);
        }
        // row 2: sorted pos 1,2,3
        {
            const float a1 = fminf(c[p][2], c[p+1][2]), a2 = fmaxf(c[p][2], c[p+1][2]);
            const float b1 = fminf(c[p+2][2], c[p+3][2]), b2 = fmaxf(c[p+2][2], c[p+3][2]);
            const float cc = c[p+4][2];
            const float M = fmaxf(a2, b2), m = fminf(a1, b1);
            const float t1 = fminf(a2, b2), t3 = fmaxf(a1, b1);
            C2 = med3f(t1, t3, cc);
            C3 = max3f(t1, fminf(cc, M), t3);
            C1 = min3f(t3, fmaxf(cc, m), t1);
        }
        // row 3: sorted pos 0,1,2
        {
            const float a1 = fminf(c[p][3], c[p+1][3]), a2 = fmaxf(c[p][3], c[p+1][3]);
            const float b1 = fminf(c[p+2][3], c[p+3][3]), b2 = fmaxf(c[p+2][3], c[p+3][3]);
            const float cc = c[p+4][3];
            const float m = fminf(a1, b1), t1 = fminf(a2, b2), t3 = fmaxf(a1, b1);
            D1 = fminf(m, cc);
            D2 = min3f(t3, fmaxf(cc, m), t1);
            D3 = med3f(t1, t3, cc);
        }
        // row 4 (column maxima): sorted pos 0,1
        {
            const float a1 = fminf(c[p][4], c[p+1][4]), a2 = fmaxf(c[p][4], c[p+1][4]);
            const float b1 = fminf(c[p+2][4], c[p+3][4]), b2 = fmaxf(c[p+2][4], c[p+3][4]);
            const float cc = c[p+4][4];
            const float m = fminf(a1, b1), t1 = fminf(a2, b2), t3 = fmaxf(a1, b1);
            E1 = fminf(m, cc);
            E2 = min3f(t3, fmaxf(cc, m), t1);
        }

        // poset elimination: 13 candidates -> 9 (rank-counted, provably safe)
        const float mn1 = fminf(B3, D3);
        const float mn2 = fminf(C3, E2);
        const float mx1 = fmaxf(B1, D1);
        const float mx2 = fmaxf(A1, C1);

        float q0 = mx2, q1 = A2, q2 = B2, q3 = C2, q4 = D2,
              q5 = E1, q6 = mx1, q7 = mn1, q8 = mn2;
        MED9(q0, q1, q2, q3, q4, q5, q6, q7, q8);
        const float mid = q4;

        // unbiased variance from shared column sums
        const float sum = (p == 0) ? sum0 : sum1;
        const float sq  = (p == 0) ? sq0  : sq1;
        const float mean = sum * (1.0f / 25.0f);
        float var = (sq - sum * mean) * (1.0f / 24.0f);
        var = fmaxf(var, 0.0f);

        const float xc = (p == 0) ? center0 : center1;
        const float rr = __builtin_amdgcn_rcpf(var + 1e-10f);
        float y = xc - noise_var * rr * (xc - mid + noise_bias);
        res[p] = fmaxf(y, 0.0f);
    }

    const int gy = tile_y + ty;
    const int gx = tile_x + tx * PXT;
    *(v2f*)&out[((size_t)b * H + gy) * W + gx] = res;
}

extern "C" void kernel_launch(void* const* d_in, const int* in_sizes, int n_in,
                              void* d_out, int out_size, void* d_ws, size_t ws_size,
                              hipStream_t stream)
{
    const float* x  = (const float*)d_in[0];
    const float* nv = (const float*)d_in[1];
    const float* nb = (const float*)d_in[2];
    float* out = (float*)d_out;

    const int H = 512, W = 512;
    const int B = in_sizes[0] / (H * W);   // 16 (C==1)

    dim3 block(BDX, BDY, 1);
    dim3 grid(W / TSX, H / TSY, B);   // (16, 32, 16) = 8192 blocks
    denoise_median5_kernel<<<grid, block, 0, stream>>>(x, nv, nb, out, H, W);
}